// Round 1
// baseline (27255.899 us; speedup 1.0000x reference)
//
#include <hip/hip_runtime.h>
#include <hip/hip_cooperative_groups.h>
#include <math.h>

namespace cg = cooperative_groups;

// Problem constants (B, ST, TT, H, E, V, O) = (64, 1024, 256, 512, 512, 32, 31)
#define B_   64
#define ST_  1024
#define TT_  256
#define H_   512
#define E_   512
#define V_   32
#define O_   31
#define G3_  1536   // 3*H

// ---------------------------------------------------------------------------
// K0a: giV[v, n] = sum_k embed[v,k] * W_ih[n,k] + b_ih[n]   (32 x 1536)
// ---------------------------------------------------------------------------
__global__ __launch_bounds__(256) void k_giv(const float* __restrict__ embed,
                                             const float* __restrict__ W_ih,
                                             const float* __restrict__ b_ih,
                                             float* __restrict__ giV) {
    int idx = blockIdx.x * 256 + threadIdx.x;       // 0 .. 49151
    if (idx >= V_ * G3_) return;
    int v = idx / G3_, n = idx % G3_;
    const float4* e4 = (const float4*)(embed + v * E_);
    const float4* w4 = (const float4*)(W_ih + (size_t)n * E_);
    float acc = 0.f;
#pragma unroll 4
    for (int k = 0; k < E_ / 4; ++k) {
        float4 a = e4[k], b = w4[k];
        acc += a.x * b.x + a.y * b.y + a.z * b.z + a.w * b.w;
    }
    giV[idx] = acc + b_ih[n];
}

// ---------------------------------------------------------------------------
// K0b: transpose fc_W (31 x 1024) -> fc_Wt (1024 x 32), pad col 31 with 0
// ---------------------------------------------------------------------------
__global__ __launch_bounds__(256) void k_fcw_t(const float* __restrict__ fc_W,
                                               float* __restrict__ fc_Wt) {
    int idx = blockIdx.x * 256 + threadIdx.x;       // 0 .. 32767
    int k = idx >> 5, o = idx & 31;
    fc_Wt[idx] = (o < O_) ? fc_W[(size_t)o * 1024 + k] : 0.f;
}

// ---------------------------------------------------------------------------
// K1p: PERSISTENT cooperative GRU — all 256 steps in one dispatch.
// Grid = 512 blocks (bc=8 x jc=64) x 256 threads, 2 blocks/CU co-resident.
// W_hh slice (8 j x 3 gates x 512) staged ONCE in LDS with per-ks padding
// ([row][4][132]) so the 8 distinct broadcast addresses per wave land on 8
// distinct bank-starts (conflict-free). h tile in [8][4][132] (4-way max).
// Thread mapping and FMA order identical to the verified k_gru_step, so
// results are bit-identical. grid.sync() between steps replaces 256 launches.
// LDS: 12672 + 4224 floats = 67584 B/block -> 132 KB/CU (<=160 KB).
// ---------------------------------------------------------------------------
__global__ __launch_bounds__(256, 2) void k_gru_all(const float* __restrict__ h0,
                                                    const float* __restrict__ giV,
                                                    const int* __restrict__ trg,
                                                    const float* __restrict__ W_hh,
                                                    const float* __restrict__ b_hh,
                                                    float* __restrict__ h_all) {
    extern __shared__ float smem[];
    float* ws  = smem;            // 24 rows x 4 ks x 132 = 12672 floats (48KB+pad)
    float* hsf = smem + 12672;    // 8 rows  x 4 ks x 132 = 4224 floats

    int tid = threadIdx.x;
    int jc = blockIdx.x & 63, bc = blockIdx.x >> 6;
    int b0 = bc * 8, j0 = jc * 8;

    // stage W_hh rows for this block's 8 j's, all 3 gates, once
    for (int i = tid; i < 3072; i += 256) {
        int r = i >> 7, rem = i & 127;          // r = g*8+jl, rem = float4 idx in row
        int ksw = rem >> 5, k4 = rem & 31;
        int g = r >> 3, jl2 = r & 7;
        *(float4*)&ws[(size_t)(r * 4 + ksw) * 132 + k4 * 4] =
            *(const float4*)(W_hh + (size_t)(g * H_ + j0 + jl2) * H_ + ksw * 128 + k4 * 4);
    }

    int bl = tid & 7;                            // batch within block
    int ks = (tid >> 3) & 3;                     // K-split id (128 each)
    int jl = tid >> 5;                           // j within block
    int j  = j0 + jl;

    const float4* w0 = (const float4*)&ws[(size_t)(( 0 + jl) * 4 + ks) * 132];
    const float4* w1 = (const float4*)&ws[(size_t)(( 8 + jl) * 4 + ks) * 132];
    const float4* w2 = (const float4*)&ws[(size_t)((16 + jl) * 4 + ks) * 132];
    const float4* h4 = (const float4*)&hsf[bl * 528 + ks * 132];

    float bhr = b_hh[j], bhz = b_hh[H_ + j], bhn = b_hh[2 * H_ + j];

    cg::grid_group grid = cg::this_grid();

    const float* hp = h0;                        // (B,H) for t=0
    size_t hstride = H_;

    for (int t = 0; t < TT_; ++t) {
        // stage h_prev rows b0..b0+7 into padded LDS tile
#pragma unroll
        for (int i = 0; i < 4; ++i) {
            int fi = tid + i * 256;              // 0..1023
            int blr = fi >> 7, k4 = fi & 127;
            float4 v = *(const float4*)(hp + (size_t)(b0 + blr) * hstride + k4 * 4);
            *(float4*)&hsf[blr * 528 + (k4 >> 5) * 132 + (k4 & 31) * 4] = v;
        }
        __syncthreads();

        float sr = 0.f, sz = 0.f, sn = 0.f;
#pragma unroll 8
        for (int k = 0; k < 32; ++k) {
            float4 hv = h4[k];
            float4 a = w0[k], c = w1[k], d = w2[k];
            sr += hv.x * a.x + hv.y * a.y + hv.z * a.z + hv.w * a.w;
            sz += hv.x * c.x + hv.y * c.y + hv.z * c.z + hv.w * c.w;
            sn += hv.x * d.x + hv.y * d.y + hv.z * d.z + hv.w * d.w;
        }
        sr += __shfl_xor(sr, 8);  sr += __shfl_xor(sr, 16);
        sz += __shfl_xor(sz, 8);  sz += __shfl_xor(sz, 16);
        sn += __shfl_xor(sn, 8);  sn += __shfl_xor(sn, 16);

        if (ks == 0) {
            int b = b0 + bl;
            int tok = trg[(size_t)b * TT_ + t];
            const float* gv = giV + (size_t)tok * G3_;
            float r = 1.f / (1.f + expf(-(gv[j] + sr + bhr)));
            float z = 1.f / (1.f + expf(-(gv[H_ + j] + sz + bhz)));
            float n = tanhf(gv[2 * H_ + j] + r * (sn + bhn));
            float hpv = hsf[bl * 528 + (j >> 7) * 132 + (j & 127)];
            h_all[(size_t)b * TT_ * H_ + (size_t)t * H_ + j] = (1.f - z) * n + z * hpv;
        }

        __threadfence();
        grid.sync();

        hp = h_all + (size_t)t * H_;             // row b is at + b*TT_*H_
        hstride = (size_t)TT_ * H_;
    }
}

// ---------------------------------------------------------------------------
// K1 (fallback): one GRU step per launch — used only if cooperative launch
// is unavailable. Identical math.
// ---------------------------------------------------------------------------
__global__ __launch_bounds__(256) void k_gru_step(const float* __restrict__ h_prev,
                                                  int hp_stride,
                                                  const float* __restrict__ giV,
                                                  const int* __restrict__ trg,
                                                  const float* __restrict__ W_hh,
                                                  const float* __restrict__ b_hh,
                                                  float* __restrict__ h_all,
                                                  int t) {
    __shared__ float hs[8][520];
    int tid = threadIdx.x;
    int jc = blockIdx.x & 63, bc = blockIdx.x >> 6;
    int b0 = bc * 8;

#pragma unroll
    for (int i = 0; i < 4; ++i) {
        int fi = tid + i * 256;
        int bl2 = fi >> 7, k4 = fi & 127;
        float4 v = *(const float4*)(h_prev + (size_t)(b0 + bl2) * hp_stride + k4 * 4);
        *(float4*)&hs[bl2][k4 * 4] = v;
    }
    __syncthreads();

    int bl = tid & 7;
    int ks = (tid >> 3) & 3;
    int jl = tid >> 5;
    int j  = jc * 8 + jl;
    int k0 = ks * 128;

    const float4* w0 = (const float4*)(W_hh + (size_t)(j         ) * H_ + k0);
    const float4* w1 = (const float4*)(W_hh + (size_t)(j +   H_  ) * H_ + k0);
    const float4* w2 = (const float4*)(W_hh + (size_t)(j + 2 * H_) * H_ + k0);
    const float4* h4 = (const float4*)&hs[bl][k0];

    float sr = 0.f, sz = 0.f, sn = 0.f;
#pragma unroll 8
    for (int k = 0; k < 32; ++k) {
        float4 hv = h4[k];
        float4 a = w0[k], c = w1[k], d = w2[k];
        sr += hv.x * a.x + hv.y * a.y + hv.z * a.z + hv.w * a.w;
        sz += hv.x * c.x + hv.y * c.y + hv.z * c.z + hv.w * c.w;
        sn += hv.x * d.x + hv.y * d.y + hv.z * d.z + hv.w * d.w;
    }
    sr += __shfl_xor(sr, 8);  sr += __shfl_xor(sr, 16);
    sz += __shfl_xor(sz, 8);  sz += __shfl_xor(sz, 16);
    sn += __shfl_xor(sn, 8);  sn += __shfl_xor(sn, 16);

    if (ks == 0) {
        int b = b0 + bl;
        int tok = trg[(size_t)b * TT_ + t];
        const float* gv = giV + (size_t)tok * G3_;
        float gh_r = sr + b_hh[j];
        float gh_z = sz + b_hh[H_ + j];
        float gh_n = sn + b_hh[2 * H_ + j];
        float r = 1.f / (1.f + expf(-(gv[j] + gh_r)));
        float z = 1.f / (1.f + expf(-(gv[H_ + j] + gh_z)));
        float n = tanhf(gv[2 * H_ + j] + r * gh_n);
        float hp = hs[bl][j];
        h_all[(size_t)b * TT_ * H_ + (size_t)t * H_ + j] = (1.f - z) * n + z * hp;
    }
}

// FMA micro-kernel helper for the 4x4 register tiles
#define FMA16(a, bb)                                                     \
    acc[0][0] = fmaf(a.x, bb.x, acc[0][0]);                              \
    acc[0][1] = fmaf(a.x, bb.y, acc[0][1]);                              \
    acc[0][2] = fmaf(a.x, bb.z, acc[0][2]);                              \
    acc[0][3] = fmaf(a.x, bb.w, acc[0][3]);                              \
    acc[1][0] = fmaf(a.y, bb.x, acc[1][0]);                              \
    acc[1][1] = fmaf(a.y, bb.y, acc[1][1]);                              \
    acc[1][2] = fmaf(a.y, bb.z, acc[1][2]);                              \
    acc[1][3] = fmaf(a.y, bb.w, acc[1][3]);                              \
    acc[2][0] = fmaf(a.z, bb.x, acc[2][0]);                              \
    acc[2][1] = fmaf(a.z, bb.y, acc[2][1]);                              \
    acc[2][2] = fmaf(a.z, bb.z, acc[2][2]);                              \
    acc[2][3] = fmaf(a.z, bb.w, acc[2][3]);                              \
    acc[3][0] = fmaf(a.w, bb.x, acc[3][0]);                              \
    acc[3][1] = fmaf(a.w, bb.y, acc[3][1]);                              \
    acc[3][2] = fmaf(a.w, bb.z, acc[3][2]);                              \
    acc[3][3] = fmaf(a.w, bb.w, acc[3][3]);

// ---------------------------------------------------------------------------
// K2: scores[b, t, s] = sum_k h_all[b,t,k] * enc[b,s,k]   (NT GEMM per batch)
// ---------------------------------------------------------------------------
__global__ __launch_bounds__(256) void k_scores(const float* __restrict__ h_all,
                                                const float* __restrict__ enc,
                                                float* __restrict__ wgt) {
    __shared__ float As[16][68];
    __shared__ float Bs[16][68];
    int b  = blockIdx.z;
    int m0 = blockIdx.y * 64, n0 = blockIdx.x * 64;
    int tid = threadIdx.x;
    int tx = tid & 15, ty = tid >> 4;
    int lr = tid >> 2, lk = (tid & 3) * 4;

    const float* Abase = h_all + (size_t)b * TT_ * H_ + (size_t)(m0 + lr) * H_ + lk;
    const float* Bbase = enc   + (size_t)b * ST_ * H_ + (size_t)(n0 + lr) * H_ + lk;

    float acc[4][4] = {};
    for (int k0 = 0; k0 < H_; k0 += 16) {
        float4 av = *(const float4*)(Abase + k0);
        float4 bv = *(const float4*)(Bbase + k0);
        __syncthreads();
        As[lk + 0][lr] = av.x; As[lk + 1][lr] = av.y;
        As[lk + 2][lr] = av.z; As[lk + 3][lr] = av.w;
        Bs[lk + 0][lr] = bv.x; Bs[lk + 1][lr] = bv.y;
        Bs[lk + 2][lr] = bv.z; Bs[lk + 3][lr] = bv.w;
        __syncthreads();
#pragma unroll
        for (int kk = 0; kk < 16; ++kk) {
            float4 a  = *(const float4*)&As[kk][ty * 4];
            float4 bb = *(const float4*)&Bs[kk][tx * 4];
            FMA16(a, bb)
        }
    }
#pragma unroll
    for (int i = 0; i < 4; ++i)
#pragma unroll
        for (int jj = 0; jj < 4; ++jj)
            wgt[(size_t)b * TT_ * ST_ + (size_t)(m0 + ty * 4 + i) * ST_ + (n0 + tx * 4 + jj)] = acc[i][jj];
}

// ---------------------------------------------------------------------------
// K3: masked softmax over s (row length 1024). One block per (b, t) row.
// ---------------------------------------------------------------------------
__global__ __launch_bounds__(256) void k_softmax(float* __restrict__ wgt,
                                                 const int* __restrict__ source_len) {
    __shared__ float red[8];
    int row = blockIdx.x;            // b*TT + t
    int b = row >> 8;
    int slen = source_len[b];
    float* W = wgt + (size_t)row * ST_;
    int tid = threadIdx.x;

    float v[4];
    float mx = -3.0e38f;
#pragma unroll
    for (int i = 0; i < 4; ++i) {
        int s = tid + i * 256;
        v[i] = (s < slen) ? W[s] : -1e9f;
        mx = fmaxf(mx, v[i]);
    }
#pragma unroll
    for (int off = 32; off; off >>= 1) mx = fmaxf(mx, __shfl_xor(mx, off));
    int wv = tid >> 6;
    if ((tid & 63) == 0) red[wv] = mx;
    __syncthreads();
    mx = fmaxf(fmaxf(red[0], red[1]), fmaxf(red[2], red[3]));

    float sm = 0.f;
#pragma unroll
    for (int i = 0; i < 4; ++i) {
        v[i] = expf(v[i] - mx);
        sm += v[i];
    }
#pragma unroll
    for (int off = 32; off; off >>= 1) sm += __shfl_xor(sm, off);
    if ((tid & 63) == 0) red[4 + wv] = sm;
    __syncthreads();
    sm = red[4] + red[5] + red[6] + red[7];
    float inv = 1.f / sm;
#pragma unroll
    for (int i = 0; i < 4; ++i)
        W[tid + i * 256] = v[i] * inv;
}

// ---------------------------------------------------------------------------
// K4: ctx[b, t, n] = sum_s wgt[b,t,s] * enc[b,s,n]   (NN GEMM per batch)
// ---------------------------------------------------------------------------
__global__ __launch_bounds__(256) void k_ctx(const float* __restrict__ wgt,
                                             const float* __restrict__ enc,
                                             float* __restrict__ ctx) {
    __shared__ float As[16][68];
    __shared__ float Bs[16][68];
    int b  = blockIdx.z;
    int m0 = blockIdx.y * 64, n0 = blockIdx.x * 64;
    int tid = threadIdx.x;
    int tx = tid & 15, ty = tid >> 4;
    int lr = tid >> 2, lk = (tid & 3) * 4;     // A-tile load mapping
    int bk = tid >> 4, bn = (tid & 15) * 4;    // B-tile load mapping

    const float* Abase = wgt + (size_t)b * TT_ * ST_ + (size_t)(m0 + lr) * ST_ + lk;
    const float* Bbase = enc + (size_t)b * ST_ * H_ + n0 + bn;

    float acc[4][4] = {};
    for (int k0 = 0; k0 < ST_; k0 += 16) {
        float4 av = *(const float4*)(Abase + k0);
        float4 bv = *(const float4*)(Bbase + (size_t)(k0 + bk) * H_);
        __syncthreads();
        As[lk + 0][lr] = av.x; As[lk + 1][lr] = av.y;
        As[lk + 2][lr] = av.z; As[lk + 3][lr] = av.w;
        *(float4*)&Bs[bk][bn] = bv;
        __syncthreads();
#pragma unroll
        for (int kk = 0; kk < 16; ++kk) {
            float4 a  = *(const float4*)&As[kk][ty * 4];
            float4 bb = *(const float4*)&Bs[kk][tx * 4];
            FMA16(a, bb)
        }
    }
#pragma unroll
    for (int i = 0; i < 4; ++i)
#pragma unroll
        for (int jj = 0; jj < 4; ++jj)
            ctx[(size_t)b * TT_ * H_ + (size_t)(m0 + ty * 4 + i) * H_ + (n0 + tx * 4 + jj)] = acc[i][jj];
}

// ---------------------------------------------------------------------------
// K5: out[b,t,o] = (t < trg_len[b]) ? [h|ctx] . fc_W[o] + fc_b[o] : 0
// ---------------------------------------------------------------------------
__global__ __launch_bounds__(256) void k_out(const float* __restrict__ h_all,
                                             const float* __restrict__ ctx,
                                             const float* __restrict__ fc_Wt,
                                             const float* __restrict__ fc_b,
                                             const int* __restrict__ trg_len,
                                             float* __restrict__ out) {
    int tid = threadIdx.x;
    int o = tid & 31;
    int m = blockIdx.x * 8 + (tid >> 5);     // b*TT + t
    int b = m >> 8, t = m & 255;
    const float* xh = h_all + (size_t)m * H_;
    const float* xc = ctx + (size_t)m * H_;
    float acc = (o < O_) ? fc_b[o] : 0.f;
#pragma unroll 4
    for (int k = 0; k < H_; ++k) acc = fmaf(xh[k], fc_Wt[k * 32 + o], acc);
#pragma unroll 4
    for (int k = 0; k < H_; ++k) acc = fmaf(xc[k], fc_Wt[(H_ + k) * 32 + o], acc);
    if (o < O_) {
        float val = (t < trg_len[b]) ? acc : 0.0f;
        out[(size_t)m * O_ + o] = val;
    }
}

// ---------------------------------------------------------------------------
extern "C" void kernel_launch(void* const* d_in, const int* in_sizes, int n_in,
                              void* d_out, int out_size, void* d_ws, size_t ws_size,
                              hipStream_t stream) {
    const int*   trg      = (const int*)d_in[0];
    const int*   trg_len  = (const int*)d_in[1];
    const int*   src_len  = (const int*)d_in[2];
    const float* enc      = (const float*)d_in[3];
    const float* enc_last = (const float*)d_in[4];
    const float* embed    = (const float*)d_in[5];
    const float* W_ih     = (const float*)d_in[6];
    const float* W_hh     = (const float*)d_in[7];
    const float* b_ih     = (const float*)d_in[8];
    const float* b_hh     = (const float*)d_in[9];
    const float* fc_W     = (const float*)d_in[10];
    const float* fc_b     = (const float*)d_in[11];
    float* out = (float*)d_out;

    char* ws = (char*)d_ws;
    float* giV   = (float*)ws;  ws += (size_t)V_ * G3_ * 4;            // 192 KB
    float* fc_Wt = (float*)ws;  ws += (size_t)1024 * 32 * 4;           // 128 KB
    float* h_all = (float*)ws;  ws += (size_t)B_ * TT_ * H_ * 4;       // 32 MB
    float* wgt   = (float*)ws;  ws += (size_t)B_ * TT_ * ST_ * 4;      // 64 MB
    float* ctx   = (float*)ws;  ws += (size_t)B_ * TT_ * H_ * 4;       // 32 MB

    k_giv<<<192, 256, 0, stream>>>(embed, W_ih, b_ih, giV);
    k_fcw_t<<<128, 256, 0, stream>>>(fc_W, fc_Wt);

    // ---- persistent cooperative GRU loop (1 dispatch instead of 256) ----
    static bool attr_set = false;
    const unsigned smem_bytes = 67584;   // (12672 + 4224) floats
    if (!attr_set) {
        // allow >64KB dynamic LDS; harmless if not required on this ROCm
        (void)hipFuncSetAttribute((const void*)k_gru_all,
                                  hipFuncAttributeMaxDynamicSharedMemorySize,
                                  (int)smem_bytes);
        attr_set = true;
    }
    void* kargs[6];
    kargs[0] = (void*)&enc_last;
    kargs[1] = (void*)&giV;
    kargs[2] = (void*)&trg;
    kargs[3] = (void*)&W_hh;
    kargs[4] = (void*)&b_hh;
    kargs[5] = (void*)&h_all;
    hipError_t ce = hipLaunchCooperativeKernel((const void*)k_gru_all,
                                               dim3(512), dim3(256),
                                               kargs, smem_bytes, stream);
    if (ce != hipSuccess) {
        (void)hipGetLastError();   // clear error; fall back to per-step loop
        for (int t = 0; t < TT_; ++t) {
            const float* hp = t ? (h_all + (size_t)(t - 1) * H_) : enc_last;
            int stride = t ? TT_ * H_ : H_;
            k_gru_step<<<512, 256, 0, stream>>>(hp, stride, giV, trg, W_hh, b_hh, h_all, t);
        }
    }

    k_scores<<<dim3(ST_ / 64, TT_ / 64, B_), 256, 0, stream>>>(h_all, enc, wgt);
    k_softmax<<<B_ * TT_, 256, 0, stream>>>(wgt, src_len);
    k_ctx<<<dim3(H_ / 64, TT_ / 64, B_), 256, 0, stream>>>(wgt, enc, ctx);
    k_out<<<B_ * TT_ / 8, 256, 0, stream>>>(h_all, ctx, fc_Wt, fc_b, trg_len, out);
}

// Round 2
// 4723.463 us; speedup vs baseline: 5.7703x; 5.7703x over previous
//
#include <hip/hip_runtime.h>
#include <math.h>

// Problem constants (B, ST, TT, H, E, V, O) = (64, 1024, 256, 512, 512, 32, 31)
#define B_   64
#define ST_  1024
#define TT_  256
#define H_   512
#define E_   512
#define V_   32
#define O_   31
#define G3_  1536   // 3*H
#define NGRP_ 8     // batch groups (bc), 64 WGs each share one barrier

// ---------------------------------------------------------------------------
// coherent-point access helpers: sc0 sc1 = write-through / L2-bypass on gfx950
// ---------------------------------------------------------------------------
__device__ __forceinline__ void load4_sc(const float* p0, const float* p1,
                                         const float* p2, const float* p3,
                                         float4& r0, float4& r1,
                                         float4& r2, float4& r3) {
    asm volatile(
        "global_load_dwordx4 %0, %4, off sc0 sc1\n\t"
        "global_load_dwordx4 %1, %5, off sc0 sc1\n\t"
        "global_load_dwordx4 %2, %6, off sc0 sc1\n\t"
        "global_load_dwordx4 %3, %7, off sc0 sc1\n\t"
        "s_waitcnt vmcnt(0)"
        : "=&v"(r0), "=&v"(r1), "=&v"(r2), "=&v"(r3)
        : "v"(p0), "v"(p1), "v"(p2), "v"(p3)
        : "memory");
}

__device__ __forceinline__ void store_sc(float* p, float v) {
    asm volatile("global_store_dword %0, %1, off sc0 sc1"
                 :: "v"(p), "v"(v) : "memory");
}

// ---------------------------------------------------------------------------
// K0a: giV[v, n] = sum_k embed[v,k] * W_ih[n,k] + b_ih[n]   (32 x 1536)
// ---------------------------------------------------------------------------
__global__ __launch_bounds__(256) void k_giv(const float* __restrict__ embed,
                                             const float* __restrict__ W_ih,
                                             const float* __restrict__ b_ih,
                                             float* __restrict__ giV) {
    int idx = blockIdx.x * 256 + threadIdx.x;       // 0 .. 49151
    if (idx >= V_ * G3_) return;
    int v = idx / G3_, n = idx % G3_;
    const float4* e4 = (const float4*)(embed + v * E_);
    const float4* w4 = (const float4*)(W_ih + (size_t)n * E_);
    float acc = 0.f;
#pragma unroll 4
    for (int k = 0; k < E_ / 4; ++k) {
        float4 a = e4[k], b = w4[k];
        acc += a.x * b.x + a.y * b.y + a.z * b.z + a.w * b.w;
    }
    giV[idx] = acc + b_ih[n];
}

// ---------------------------------------------------------------------------
// K0b: transpose fc_W -> fc_Wt (1024 x 32) and zero the barrier counters
// ---------------------------------------------------------------------------
__global__ __launch_bounds__(256) void k_fcw_t(const float* __restrict__ fc_W,
                                               float* __restrict__ fc_Wt,
                                               unsigned* __restrict__ cnt) {
    int idx = blockIdx.x * 256 + threadIdx.x;       // 0 .. 32767
    int k = idx >> 5, o = idx & 31;
    fc_Wt[idx] = (o < O_) ? fc_W[(size_t)o * 1024 + k] : 0.f;
    if (idx < TT_ * NGRP_) cnt[idx] = 0u;           // 2048 counters
}

// ---------------------------------------------------------------------------
// K1p: persistent GRU, all 256 steps in one dispatch.
// Grid = 512 WGs (bc=8 x jc=64) x 256 thr, 2 WGs/CU (cooperative launch used
// ONLY for the co-residency guarantee — no grid.sync()).
// Cross-WG h exchange goes through the device-coherent point via sc0/sc1
// stores+loads; per-step sync is 8 independent 64-WG counter barriers.
// W_hh slice staged once in LDS ([row][4][132] padding, conflict-free
// broadcast reads). Math identical to the verified per-step kernel.
// ---------------------------------------------------------------------------
__global__ __launch_bounds__(256, 2) void k_gru_persist(
        const float* __restrict__ h0,
        const float* __restrict__ giV,
        const int* __restrict__ trg,
        const float* __restrict__ W_hh,
        const float* __restrict__ b_hh,
        float* __restrict__ h_all,
        unsigned* __restrict__ cnt) {
    extern __shared__ float smem[];
    float* ws  = smem;            // 24 rows x 4 ks x 132 = 12672 floats
    float* hsf = smem + 12672;    // 8 rows  x 4 ks x 132 = 4224 floats

    int tid = threadIdx.x;
    int jc = blockIdx.x & 63, bc = blockIdx.x >> 6;
    int b0 = bc * 8, j0 = jc * 8;

    // stage W_hh rows for this block's 8 j's, all 3 gates, once (cached loads)
    for (int i = tid; i < 3072; i += 256) {
        int r = i >> 7, rem = i & 127;          // r = g*8+jl, rem = float4 idx
        int ksw = rem >> 5, k4 = rem & 31;
        int g = r >> 3, jl2 = r & 7;
        *(float4*)&ws[(size_t)(r * 4 + ksw) * 132 + k4 * 4] =
            *(const float4*)(W_hh + (size_t)(g * H_ + j0 + jl2) * H_ + ksw * 128 + k4 * 4);
    }

    int bl = tid & 7;                            // batch within block
    int ks = (tid >> 3) & 3;                     // K-split id (128 each)
    int jl = tid >> 5;                           // j within block
    int j  = j0 + jl;

    const float4* w0 = (const float4*)&ws[(size_t)(( 0 + jl) * 4 + ks) * 132];
    const float4* w1 = (const float4*)&ws[(size_t)(( 8 + jl) * 4 + ks) * 132];
    const float4* w2 = (const float4*)&ws[(size_t)((16 + jl) * 4 + ks) * 132];
    const float4* h4 = (const float4*)&hsf[bl * 528 + ks * 132];

    float bhr = b_hh[j], bhz = b_hh[H_ + j], bhn = b_hh[2 * H_ + j];

    // staging geometry: k4s = float4 index within a row (constant per thread),
    // rows handled: (tid>>7) + 2*i for i=0..3
    int k4s = tid & 127, rw = tid >> 7;
    int lds_off = (k4s >> 5) * 132 + (k4s & 31) * 4;

    for (int t = 0; t < TT_; ++t) {
        if (t == 0) {
#pragma unroll
            for (int i = 0; i < 4; ++i) {
                int row = rw + 2 * i;
                float4 v = *(const float4*)(h0 + (size_t)(b0 + row) * H_ + k4s * 4);
                *(float4*)&hsf[row * 528 + lds_off] = v;
            }
        } else {
            const float* pb = h_all + (size_t)(t - 1) * H_ + (size_t)k4s * 4;
            const float* p0v = pb + (size_t)(b0 + rw + 0) * (TT_ * H_);
            const float* p1v = pb + (size_t)(b0 + rw + 2) * (TT_ * H_);
            const float* p2v = pb + (size_t)(b0 + rw + 4) * (TT_ * H_);
            const float* p3v = pb + (size_t)(b0 + rw + 6) * (TT_ * H_);
            float4 r0v, r1v, r2v, r3v;
            load4_sc(p0v, p1v, p2v, p3v, r0v, r1v, r2v, r3v);
            *(float4*)&hsf[(rw + 0) * 528 + lds_off] = r0v;
            *(float4*)&hsf[(rw + 2) * 528 + lds_off] = r1v;
            *(float4*)&hsf[(rw + 4) * 528 + lds_off] = r2v;
            *(float4*)&hsf[(rw + 6) * 528 + lds_off] = r3v;
        }
        __syncthreads();

        float sr = 0.f, sz = 0.f, sn = 0.f;
#pragma unroll 8
        for (int k = 0; k < 32; ++k) {
            float4 hv = h4[k];
            float4 a = w0[k], c = w1[k], d = w2[k];
            sr += hv.x * a.x + hv.y * a.y + hv.z * a.z + hv.w * a.w;
            sz += hv.x * c.x + hv.y * c.y + hv.z * c.z + hv.w * c.w;
            sn += hv.x * d.x + hv.y * d.y + hv.z * d.z + hv.w * d.w;
        }
        sr += __shfl_xor(sr, 8);  sr += __shfl_xor(sr, 16);
        sz += __shfl_xor(sz, 8);  sz += __shfl_xor(sz, 16);
        sn += __shfl_xor(sn, 8);  sn += __shfl_xor(sn, 16);

        if (ks == 0) {
            int b = b0 + bl;
            int tok = trg[(size_t)b * TT_ + t];
            const float* gv = giV + (size_t)tok * G3_;
            float r = 1.f / (1.f + expf(-(gv[j] + sr + bhr)));
            float z = 1.f / (1.f + expf(-(gv[H_ + j] + sz + bhz)));
            float n = tanhf(gv[2 * H_ + j] + r * (sn + bhn));
            float hpv = hsf[bl * 528 + (j >> 7) * 132 + (j & 127)];
            store_sc(h_all + (size_t)b * TT_ * H_ + (size_t)t * H_ + j,
                     (1.f - z) * n + z * hpv);
        }

        // make this wave's write-through stores reach the coherent point
        asm volatile("s_waitcnt vmcnt(0)" ::: "memory");
        __syncthreads();   // all waves of the WG done writing h[t]

        if (t < TT_ - 1) {
            if (tid == 0) {
                unsigned* c = cnt + t * NGRP_ + bc;
                __hip_atomic_fetch_add(c, 1u, __ATOMIC_RELAXED,
                                       __HIP_MEMORY_SCOPE_AGENT);
                int guard = 0;
                while (__hip_atomic_load(c, __ATOMIC_RELAXED,
                                         __HIP_MEMORY_SCOPE_AGENT) < 64u) {
                    __builtin_amdgcn_s_sleep(4);
                    if (++guard > (1 << 24)) break;   // safety valve
                }
            }
            __syncthreads();   // release whole WG once group barrier passed
        }
    }
}

// ---------------------------------------------------------------------------
// K1 (fallback): one GRU step per launch — used only if cooperative launch
// is unavailable. Identical math.
// ---------------------------------------------------------------------------
__global__ __launch_bounds__(256) void k_gru_step(const float* __restrict__ h_prev,
                                                  int hp_stride,
                                                  const float* __restrict__ giV,
                                                  const int* __restrict__ trg,
                                                  const float* __restrict__ W_hh,
                                                  const float* __restrict__ b_hh,
                                                  float* __restrict__ h_all,
                                                  int t) {
    __shared__ float hs[8][520];
    int tid = threadIdx.x;
    int jc = blockIdx.x & 63, bc = blockIdx.x >> 6;
    int b0 = bc * 8;

#pragma unroll
    for (int i = 0; i < 4; ++i) {
        int fi = tid + i * 256;
        int bl2 = fi >> 7, k4 = fi & 127;
        float4 v = *(const float4*)(h_prev + (size_t)(b0 + bl2) * hp_stride + k4 * 4);
        *(float4*)&hs[bl2][k4 * 4] = v;
    }
    __syncthreads();

    int bl = tid & 7;
    int ks = (tid >> 3) & 3;
    int jl = tid >> 5;
    int j  = jc * 8 + jl;
    int k0 = ks * 128;

    const float4* w0 = (const float4*)(W_hh + (size_t)(j         ) * H_ + k0);
    const float4* w1 = (const float4*)(W_hh + (size_t)(j +   H_  ) * H_ + k0);
    const float4* w2 = (const float4*)(W_hh + (size_t)(j + 2 * H_) * H_ + k0);
    const float4* h4 = (const float4*)&hs[bl][k0];

    float sr = 0.f, sz = 0.f, sn = 0.f;
#pragma unroll 8
    for (int k = 0; k < 32; ++k) {
        float4 hv = h4[k];
        float4 a = w0[k], c = w1[k], d = w2[k];
        sr += hv.x * a.x + hv.y * a.y + hv.z * a.z + hv.w * a.w;
        sz += hv.x * c.x + hv.y * c.y + hv.z * c.z + hv.w * c.w;
        sn += hv.x * d.x + hv.y * d.y + hv.z * d.z + hv.w * d.w;
    }
    sr += __shfl_xor(sr, 8);  sr += __shfl_xor(sr, 16);
    sz += __shfl_xor(sz, 8);  sz += __shfl_xor(sz, 16);
    sn += __shfl_xor(sn, 8);  sn += __shfl_xor(sn, 16);

    if (ks == 0) {
        int b = b0 + bl;
        int tok = trg[(size_t)b * TT_ + t];
        const float* gv = giV + (size_t)tok * G3_;
        float gh_r = sr + b_hh[j];
        float gh_z = sz + b_hh[H_ + j];
        float gh_n = sn + b_hh[2 * H_ + j];
        float r = 1.f / (1.f + expf(-(gv[j] + gh_r)));
        float z = 1.f / (1.f + expf(-(gv[H_ + j] + gh_z)));
        float n = tanhf(gv[2 * H_ + j] + r * gh_n);
        float hp = hs[bl][j];
        h_all[(size_t)b * TT_ * H_ + (size_t)t * H_ + j] = (1.f - z) * n + z * hp;
    }
}

// FMA micro-kernel helper for the 4x4 register tiles
#define FMA16(a, bb)                                                     \
    acc[0][0] = fmaf(a.x, bb.x, acc[0][0]);                              \
    acc[0][1] = fmaf(a.x, bb.y, acc[0][1]);                              \
    acc[0][2] = fmaf(a.x, bb.z, acc[0][2]);                              \
    acc[0][3] = fmaf(a.x, bb.w, acc[0][3]);                              \
    acc[1][0] = fmaf(a.y, bb.x, acc[1][0]);                              \
    acc[1][1] = fmaf(a.y, bb.y, acc[1][1]);                              \
    acc[1][2] = fmaf(a.y, bb.z, acc[1][2]);                              \
    acc[1][3] = fmaf(a.y, bb.w, acc[1][3]);                              \
    acc[2][0] = fmaf(a.z, bb.x, acc[2][0]);                              \
    acc[2][1] = fmaf(a.z, bb.y, acc[2][1]);                              \
    acc[2][2] = fmaf(a.z, bb.z, acc[2][2]);                              \
    acc[2][3] = fmaf(a.z, bb.w, acc[2][3]);                              \
    acc[3][0] = fmaf(a.w, bb.x, acc[3][0]);                              \
    acc[3][1] = fmaf(a.w, bb.y, acc[3][1]);                              \
    acc[3][2] = fmaf(a.w, bb.z, acc[3][2]);                              \
    acc[3][3] = fmaf(a.w, bb.w, acc[3][3]);

// ---------------------------------------------------------------------------
// K2: scores[b, t, s] = sum_k h_all[b,t,k] * enc[b,s,k]   (NT GEMM per batch)
// ---------------------------------------------------------------------------
__global__ __launch_bounds__(256) void k_scores(const float* __restrict__ h_all,
                                                const float* __restrict__ enc,
                                                float* __restrict__ wgt) {
    __shared__ float As[16][68];
    __shared__ float Bs[16][68];
    int b  = blockIdx.z;
    int m0 = blockIdx.y * 64, n0 = blockIdx.x * 64;
    int tid = threadIdx.x;
    int tx = tid & 15, ty = tid >> 4;
    int lr = tid >> 2, lk = (tid & 3) * 4;

    const float* Abase = h_all + (size_t)b * TT_ * H_ + (size_t)(m0 + lr) * H_ + lk;
    const float* Bbase = enc   + (size_t)b * ST_ * H_ + (size_t)(n0 + lr) * H_ + lk;

    float acc[4][4] = {};
    for (int k0 = 0; k0 < H_; k0 += 16) {
        float4 av = *(const float4*)(Abase + k0);
        float4 bv = *(const float4*)(Bbase + k0);
        __syncthreads();
        As[lk + 0][lr] = av.x; As[lk + 1][lr] = av.y;
        As[lk + 2][lr] = av.z; As[lk + 3][lr] = av.w;
        Bs[lk + 0][lr] = bv.x; Bs[lk + 1][lr] = bv.y;
        Bs[lk + 2][lr] = bv.z; Bs[lk + 3][lr] = bv.w;
        __syncthreads();
#pragma unroll
        for (int kk = 0; kk < 16; ++kk) {
            float4 a  = *(const float4*)&As[kk][ty * 4];
            float4 bb = *(const float4*)&Bs[kk][tx * 4];
            FMA16(a, bb)
        }
    }
#pragma unroll
    for (int i = 0; i < 4; ++i)
#pragma unroll
        for (int jj = 0; jj < 4; ++jj)
            wgt[(size_t)b * TT_ * ST_ + (size_t)(m0 + ty * 4 + i) * ST_ + (n0 + tx * 4 + jj)] = acc[i][jj];
}

// ---------------------------------------------------------------------------
// K3: masked softmax over s (row length 1024). One block per (b, t) row.
// ---------------------------------------------------------------------------
__global__ __launch_bounds__(256) void k_softmax(float* __restrict__ wgt,
                                                 const int* __restrict__ source_len) {
    __shared__ float red[8];
    int row = blockIdx.x;            // b*TT + t
    int b = row >> 8;
    int slen = source_len[b];
    float* W = wgt + (size_t)row * ST_;
    int tid = threadIdx.x;

    float v[4];
    float mx = -3.0e38f;
#pragma unroll
    for (int i = 0; i < 4; ++i) {
        int s = tid + i * 256;
        v[i] = (s < slen) ? W[s] : -1e9f;
        mx = fmaxf(mx, v[i]);
    }
#pragma unroll
    for (int off = 32; off; off >>= 1) mx = fmaxf(mx, __shfl_xor(mx, off));
    int wv = tid >> 6;
    if ((tid & 63) == 0) red[wv] = mx;
    __syncthreads();
    mx = fmaxf(fmaxf(red[0], red[1]), fmaxf(red[2], red[3]));

    float sm = 0.f;
#pragma unroll
    for (int i = 0; i < 4; ++i) {
        v[i] = expf(v[i] - mx);
        sm += v[i];
    }
#pragma unroll
    for (int off = 32; off; off >>= 1) sm += __shfl_xor(sm, off);
    if ((tid & 63) == 0) red[4 + wv] = sm;
    __syncthreads();
    sm = red[4] + red[5] + red[6] + red[7];
    float inv = 1.f / sm;
#pragma unroll
    for (int i = 0; i < 4; ++i)
        W[tid + i * 256] = v[i] * inv;
}

// ---------------------------------------------------------------------------
// K4: ctx[b, t, n] = sum_s wgt[b,t,s] * enc[b,s,n]   (NN GEMM per batch)
// ---------------------------------------------------------------------------
__global__ __launch_bounds__(256) void k_ctx(const float* __restrict__ wgt,
                                             const float* __restrict__ enc,
                                             float* __restrict__ ctx) {
    __shared__ float As[16][68];
    __shared__ float Bs[16][68];
    int b  = blockIdx.z;
    int m0 = blockIdx.y * 64, n0 = blockIdx.x * 64;
    int tid = threadIdx.x;
    int tx = tid & 15, ty = tid >> 4;
    int lr = tid >> 2, lk = (tid & 3) * 4;     // A-tile load mapping
    int bk = tid >> 4, bn = (tid & 15) * 4;    // B-tile load mapping

    const float* Abase = wgt + (size_t)b * TT_ * ST_ + (size_t)(m0 + lr) * ST_ + lk;
    const float* Bbase = enc + (size_t)b * ST_ * H_ + n0 + bn;

    float acc[4][4] = {};
    for (int k0 = 0; k0 < ST_; k0 += 16) {
        float4 av = *(const float4*)(Abase + k0);
        float4 bv = *(const float4*)(Bbase + (size_t)(k0 + bk) * H_);
        __syncthreads();
        As[lk + 0][lr] = av.x; As[lk + 1][lr] = av.y;
        As[lk + 2][lr] = av.z; As[lk + 3][lr] = av.w;
        *(float4*)&Bs[bk][bn] = bv;
        __syncthreads();
#pragma unroll
        for (int kk = 0; kk < 16; ++kk) {
            float4 a  = *(const float4*)&As[kk][ty * 4];
            float4 bb = *(const float4*)&Bs[kk][tx * 4];
            FMA16(a, bb)
        }
    }
#pragma unroll
    for (int i = 0; i < 4; ++i)
#pragma unroll
        for (int jj = 0; jj < 4; ++jj)
            ctx[(size_t)b * TT_ * H_ + (size_t)(m0 + ty * 4 + i) * H_ + (n0 + tx * 4 + jj)] = acc[i][jj];
}

// ---------------------------------------------------------------------------
// K5: out[b,t,o] = (t < trg_len[b]) ? [h|ctx] . fc_W[o] + fc_b[o] : 0
// ---------------------------------------------------------------------------
__global__ __launch_bounds__(256) void k_out(const float* __restrict__ h_all,
                                             const float* __restrict__ ctx,
                                             const float* __restrict__ fc_Wt,
                                             const float* __restrict__ fc_b,
                                             const int* __restrict__ trg_len,
                                             float* __restrict__ out) {
    int tid = threadIdx.x;
    int o = tid & 31;
    int m = blockIdx.x * 8 + (tid >> 5);     // b*TT + t
    int b = m >> 8, t = m & 255;
    const float* xh = h_all + (size_t)m * H_;
    const float* xc = ctx + (size_t)m * H_;
    float acc = (o < O_) ? fc_b[o] : 0.f;
#pragma unroll 4
    for (int k = 0; k < H_; ++k) acc = fmaf(xh[k], fc_Wt[k * 32 + o], acc);
#pragma unroll 4
    for (int k = 0; k < H_; ++k) acc = fmaf(xc[k], fc_Wt[(H_ + k) * 32 + o], acc);
    if (o < O_) {
        float val = (t < trg_len[b]) ? acc : 0.0f;
        out[(size_t)m * O_ + o] = val;
    }
}

// ---------------------------------------------------------------------------
extern "C" void kernel_launch(void* const* d_in, const int* in_sizes, int n_in,
                              void* d_out, int out_size, void* d_ws, size_t ws_size,
                              hipStream_t stream) {
    const int*   trg      = (const int*)d_in[0];
    const int*   trg_len  = (const int*)d_in[1];
    const int*   src_len  = (const int*)d_in[2];
    const float* enc      = (const float*)d_in[3];
    const float* enc_last = (const float*)d_in[4];
    const float* embed    = (const float*)d_in[5];
    const float* W_ih     = (const float*)d_in[6];
    const float* W_hh     = (const float*)d_in[7];
    const float* b_ih     = (const float*)d_in[8];
    const float* b_hh     = (const float*)d_in[9];
    const float* fc_W     = (const float*)d_in[10];
    const float* fc_b     = (const float*)d_in[11];
    float* out = (float*)d_out;

    char* ws = (char*)d_ws;
    float* giV   = (float*)ws;  ws += (size_t)V_ * G3_ * 4;            // 192 KB
    float* fc_Wt = (float*)ws;  ws += (size_t)1024 * 32 * 4;           // 128 KB
    float* h_all = (float*)ws;  ws += (size_t)B_ * TT_ * H_ * 4;       // 32 MB
    float* wgt   = (float*)ws;  ws += (size_t)B_ * TT_ * ST_ * 4;      // 64 MB
    float* ctx   = (float*)ws;  ws += (size_t)B_ * TT_ * H_ * 4;       // 32 MB
    unsigned* cnt = (unsigned*)ws; ws += (size_t)TT_ * NGRP_ * 4;      // 8 KB

    k_giv<<<192, 256, 0, stream>>>(embed, W_ih, b_ih, giV);
    k_fcw_t<<<128, 256, 0, stream>>>(fc_W, fc_Wt, cnt);

    // ---- persistent GRU (co-residency via cooperative launch; own sync) ----
    static bool attr_set = false;
    const unsigned smem_bytes = 67584;   // (12672 + 4224) floats
    if (!attr_set) {
        (void)hipFuncSetAttribute((const void*)k_gru_persist,
                                  hipFuncAttributeMaxDynamicSharedMemorySize,
                                  (int)smem_bytes);
        attr_set = true;
    }
    void* kargs[7];
    kargs[0] = (void*)&enc_last;
    kargs[1] = (void*)&giV;
    kargs[2] = (void*)&trg;
    kargs[3] = (void*)&W_hh;
    kargs[4] = (void*)&b_hh;
    kargs[5] = (void*)&h_all;
    kargs[6] = (void*)&cnt;
    hipError_t ce = hipLaunchCooperativeKernel((const void*)k_gru_persist,
                                               dim3(512), dim3(256),
                                               kargs, smem_bytes, stream);
    if (ce != hipSuccess) {
        (void)hipGetLastError();   // clear error; fall back to per-step loop
        for (int t = 0; t < TT_; ++t) {
            const float* hp = t ? (h_all + (size_t)(t - 1) * H_) : enc_last;
            int stride = t ? TT_ * H_ : H_;
            k_gru_step<<<512, 256, 0, stream>>>(hp, stride, giV, trg, W_hh, b_hh, h_all, t);
        }
    }

    k_scores<<<dim3(ST_ / 64, TT_ / 64, B_), 256, 0, stream>>>(h_all, enc, wgt);
    k_softmax<<<B_ * TT_, 256, 0, stream>>>(wgt, src_len);
    k_ctx<<<dim3(H_ / 64, TT_ / 64, B_), 256, 0, stream>>>(wgt, enc, ctx);
    k_out<<<B_ * TT_ / 8, 256, 0, stream>>>(h_all, ctx, fc_Wt, fc_b, trg_len, out);
}